// Round 1
// baseline (6240.017 us; speedup 1.0000x reference)
//
#include <hip/hip_runtime.h>
#include <hip/hip_bf16.h>

#define DEVI __device__ __forceinline__

constexpr int NN = 10000;   // nodes
constexpr int NE = 80000;   // edges

// ---------- bf16 helpers (bit-level, RNE) ----------
DEVI float b2f(unsigned short u) {
  union { unsigned int i; float f; } c; c.i = ((unsigned int)u) << 16; return c.f;
}
DEVI unsigned short f2b(float f) {
  union { float f; unsigned int i; } c; c.f = f;
  unsigned int i = c.i;
  unsigned int r = (i + 0x7fffu + ((i >> 16) & 1u)) >> 16;
  return (unsigned short)r;
}

DEVI void load4(const float* p, float v[4]) {
  float4 t = *reinterpret_cast<const float4*>(p);
  v[0] = t.x; v[1] = t.y; v[2] = t.z; v[3] = t.w;
}
DEVI void load4(const __hip_bfloat16* p, float v[4]) {
  ushort4 t = *reinterpret_cast<const ushort4*>(p);
  v[0] = b2f(t.x); v[1] = b2f(t.y); v[2] = b2f(t.z); v[3] = b2f(t.w);
}
DEVI void store4(float* p, const float v[4]) {
  *reinterpret_cast<float4*>(p) = make_float4(v[0], v[1], v[2], v[3]);
}
DEVI void store4(__hip_bfloat16* p, const float v[4]) {
  ushort4 u; u.x = f2b(v[0]); u.y = f2b(v[1]); u.z = f2b(v[2]); u.w = f2b(v[3]);
  *reinterpret_cast<ushort4*>(p) = u;
}

// ---------- edge message + scatter-add ----------
// thread handles one (edge, 4-channel) chunk. lcq = log2(C/4).
template <typename XT>
__global__ __launch_bounds__(256)
void scatter_kernel(const XT* __restrict__ x, const float* __restrict__ pos,
                    const int* __restrict__ src, const int* __restrict__ dst,
                    const float* __restrict__ Win,  // [2,C]
                    const float* __restrict__ bin,  // [C]
                    float* __restrict__ agg,        // [NN,C], pre-zeroed
                    int C, int lcq) {
  int idx = blockIdx.x * 256 + threadIdx.x;
  int e = idx >> lcq;
  if (e >= NE) return;
  int c = (idx & ((1 << lcq) - 1)) << 2;
  int s = src[e], d = dst[e];
  float2 ps = *reinterpret_cast<const float2*>(pos + 2 * s);
  float2 pd = *reinterpret_cast<const float2*>(pos + 2 * d);
  float rx = ps.x - pd.x, ry = ps.y - pd.y;   // pos_j - pos_i (j=src, i=dst)
  float w0[4], w1[4], bb[4], xv[4];
  load4(Win + c, w0);
  load4(Win + C + c, w1);
  load4(bin + c, bb);
  load4(x + (size_t)s * C + c, xv);
  float* ap = agg + (size_t)d * C + c;
#pragma unroll
  for (int j = 0; j < 4; ++j) {
    float sc = fmaxf(fmaf(rx, w0[j], fmaf(ry, w1[j], bb[j])), 0.f);
    atomicAdd(ap + j, sc * xv[j]);
  }
}

// ---------- f32 tiled GEMM: out = relu(A[M,K] @ B[K,N] + bias) ----------
// 64x64 tile, 16 K-step, 256 threads, 4x4 microtile.
template <typename OT>
__global__ __launch_bounds__(256)
void gemm_bias_relu(const float* __restrict__ A, const float* __restrict__ B,
                    const float* __restrict__ bias, OT* __restrict__ out,
                    int M, int N, int K) {
  __shared__ float As[64][17];   // [m][k], pad 17 to spread banks
  __shared__ float Bs[16][72];   // [k][n], pad 72 (288B rows, float4-aligned)
  const int t = threadIdx.x;
  const int tx = t & 15, ty = t >> 4;
  const int m0 = blockIdx.y * 64, n0 = blockIdx.x * 64;
  const int ar = t >> 2, ak = (t & 3) << 2;   // A staging: row 0..63, k 0..12
  const int br = t >> 4, bn = (t & 15) << 2;  // B staging: k 0..15, n 0..60
  float acc[4][4] = {};
  for (int k0 = 0; k0 < K; k0 += 16) {
    float4 av;
    int gm = m0 + ar;
    if (gm < M) av = *reinterpret_cast<const float4*>(&A[(size_t)gm * K + k0 + ak]);
    else av = make_float4(0.f, 0.f, 0.f, 0.f);
    float4 bv = *reinterpret_cast<const float4*>(&B[(size_t)(k0 + br) * N + n0 + bn]);
    As[ar][ak] = av.x; As[ar][ak + 1] = av.y; As[ar][ak + 2] = av.z; As[ar][ak + 3] = av.w;
    *reinterpret_cast<float4*>(&Bs[br][bn]) = bv;
    __syncthreads();
#pragma unroll
    for (int k = 0; k < 16; ++k) {
      float a0 = As[ty * 4 + 0][k], a1 = As[ty * 4 + 1][k];
      float a2 = As[ty * 4 + 2][k], a3 = As[ty * 4 + 3][k];
      float4 b = *reinterpret_cast<const float4*>(&Bs[k][tx * 4]);
      acc[0][0] = fmaf(a0, b.x, acc[0][0]); acc[0][1] = fmaf(a0, b.y, acc[0][1]);
      acc[0][2] = fmaf(a0, b.z, acc[0][2]); acc[0][3] = fmaf(a0, b.w, acc[0][3]);
      acc[1][0] = fmaf(a1, b.x, acc[1][0]); acc[1][1] = fmaf(a1, b.y, acc[1][1]);
      acc[1][2] = fmaf(a1, b.z, acc[1][2]); acc[1][3] = fmaf(a1, b.w, acc[1][3]);
      acc[2][0] = fmaf(a2, b.x, acc[2][0]); acc[2][1] = fmaf(a2, b.y, acc[2][1]);
      acc[2][2] = fmaf(a2, b.z, acc[2][2]); acc[2][3] = fmaf(a2, b.w, acc[2][3]);
      acc[3][0] = fmaf(a3, b.x, acc[3][0]); acc[3][1] = fmaf(a3, b.y, acc[3][1]);
      acc[3][2] = fmaf(a3, b.z, acc[3][2]); acc[3][3] = fmaf(a3, b.w, acc[3][3]);
    }
    __syncthreads();
  }
#pragma unroll
  for (int i = 0; i < 4; ++i) {
    int gm = m0 + ty * 4 + i;
    if (gm < M) {
      float v[4];
#pragma unroll
      for (int j = 0; j < 4; ++j)
        v[j] = fmaxf(acc[i][j] + bias[n0 + tx * 4 + j], 0.f);
      store4(out + (size_t)gm * N + n0 + tx * 4, v);
    }
  }
}

// ---------- row-wise L2 normalize, C=1024, one block per row ----------
__global__ __launch_bounds__(256)
void l2norm_kernel(float* __restrict__ out) {
  constexpr int C = 1024;
  float* p = out + (size_t)blockIdx.x * C;
  float4 v = *reinterpret_cast<const float4*>(p + threadIdx.x * 4);
  float s = v.x * v.x + v.y * v.y + v.z * v.z + v.w * v.w;
#pragma unroll
  for (int o = 32; o > 0; o >>= 1) s += __shfl_down(s, o);
  __shared__ float wsum[4];
  if ((threadIdx.x & 63) == 0) wsum[threadIdx.x >> 6] = s;
  __syncthreads();
  float tot = wsum[0] + wsum[1] + wsum[2] + wsum[3];
  float inv = 1.0f / fmaxf(sqrtf(tot), 1e-12f);
  float4 r = make_float4(v.x * inv, v.y * inv, v.z * inv, v.w * inv);
  *reinterpret_cast<float4*>(p + threadIdx.x * 4) = r;
}

extern "C" void kernel_launch(void* const* d_in, const int* in_sizes, int n_in,
                              void* d_out, int out_size, void* d_ws, size_t ws_size,
                              hipStream_t stream) {
  (void)in_sizes; (void)n_in; (void)out_size; (void)ws_size;
  const float* x     = (const float*)d_in[0];
  const float* pos   = (const float*)d_in[1];
  const int*   ei    = (const int*)d_in[2];
  const int*   srcv  = ei;            // edge_index[0]
  const int*   dstv  = ei + NE;       // edge_index[1]
  const float* Win1  = (const float*)d_in[3];
  const float* bin1  = (const float*)d_in[4];
  const float* Wout1 = (const float*)d_in[5];
  const float* bout1 = (const float*)d_in[6];
  const float* Win2  = (const float*)d_in[7];
  const float* bin2  = (const float*)d_in[8];
  const float* Wout2 = (const float*)d_in[9];
  const float* bout2 = (const float*)d_in[10];
  const float* Win3  = (const float*)d_in[11];
  const float* bin3  = (const float*)d_in[12];
  const float* Wout3 = (const float*)d_in[13];
  const float* bout3 = (const float*)d_in[14];
  float* outp = (float*)d_out;

  // workspace layout
  char* ws = (char*)d_ws;
  float* agg = (float*)ws;                                        // 10000*2048*4 = 81,920,000 B
  __hip_bfloat16* h1 = (__hip_bfloat16*)(ws + 81920000);          // 10000*2048*2 = 40,960,000 B
  __hip_bfloat16* h2 = (__hip_bfloat16*)(ws + 81920000 + 40960000);

  const dim3 blk(256);

  // ---- layer 1: C_in=128 -> H1=2048 ----
  hipMemsetAsync(agg, 0, (size_t)NN * 128 * 4, stream);
  {
    int total = NE * (128 / 4);
    scatter_kernel<float><<<(total + 255) / 256, blk, 0, stream>>>(
        x, pos, srcv, dstv, Win1, bin1, agg, 128, 5);
  }
  gemm_bias_relu<__hip_bfloat16><<<dim3(2048 / 64, (NN + 63) / 64), blk, 0, stream>>>(
      agg, Wout1, bout1, h1, NN, 2048, 128);

  // ---- layer 2: 2048 -> 2048 ----
  hipMemsetAsync(agg, 0, (size_t)NN * 2048 * 4, stream);
  {
    int total = NE * (2048 / 4);
    scatter_kernel<__hip_bfloat16><<<(total + 255) / 256, blk, 0, stream>>>(
        h1, pos, srcv, dstv, Win2, bin2, agg, 2048, 9);
  }
  gemm_bias_relu<__hip_bfloat16><<<dim3(2048 / 64, (NN + 63) / 64), blk, 0, stream>>>(
      agg, Wout2, bout2, h2, NN, 2048, 2048);

  // ---- layer 3: 2048 -> 1024 ----
  hipMemsetAsync(agg, 0, (size_t)NN * 2048 * 4, stream);
  {
    int total = NE * (2048 / 4);
    scatter_kernel<__hip_bfloat16><<<(total + 255) / 256, blk, 0, stream>>>(
        h2, pos, srcv, dstv, Win3, bin3, agg, 2048, 9);
  }
  gemm_bias_relu<float><<<dim3(1024 / 64, (NN + 63) / 64), blk, 0, stream>>>(
      agg, Wout3, bout3, outp, NN, 1024, 2048);

  // ---- final L2 normalize ----
  l2norm_kernel<<<NN, blk, 0, stream>>>(outp);
}

// Round 2
// 1989.112 us; speedup vs baseline: 3.1371x; 3.1371x over previous
//
#include <hip/hip_runtime.h>
#include <hip/hip_bf16.h>

#define DEVI __device__ __forceinline__

constexpr int NN = 10000;   // nodes
constexpr int NE = 80000;   // edges

// ---------- bf16 helpers (bit-level, RNE) ----------
DEVI float b2f(unsigned short u) {
  union { unsigned int i; float f; } c; c.i = ((unsigned int)u) << 16; return c.f;
}
DEVI float blo(unsigned int u) {  // bf16 in low 16 bits
  union { unsigned int i; float f; } c; c.i = u << 16; return c.f;
}
DEVI float bhi(unsigned int u) {  // bf16 in high 16 bits
  union { unsigned int i; float f; } c; c.i = u & 0xffff0000u; return c.f;
}
DEVI unsigned short f2b(float f) {
  union { float f; unsigned int i; } c; c.f = f;
  unsigned int i = c.i;
  unsigned int r = (i + 0x7fffu + ((i >> 16) & 1u)) >> 16;
  return (unsigned short)r;
}
DEVI void store4(float* p, const float v[4]) {
  *reinterpret_cast<float4*>(p) = make_float4(v[0], v[1], v[2], v[3]);
}
DEVI void store4(__hip_bfloat16* p, const float v[4]) {
  ushort4 u; u.x = f2b(v[0]); u.y = f2b(v[1]); u.z = f2b(v[2]); u.w = f2b(v[3]);
  *reinterpret_cast<ushort4*>(p) = u;
}

// ================= CSR build =================
__global__ __launch_bounds__(256)
void hist_kernel(const int* __restrict__ dst, int* __restrict__ cnt) {
  int e = blockIdx.x * 256 + threadIdx.x;
  if (e < NE) atomicAdd(&cnt[dst[e]], 1);
}

// single-block exclusive scan over NN counts -> off, cursor
__global__ __launch_bounds__(256)
void scan_kernel(const int* __restrict__ cnt, int* __restrict__ off,
                 int* __restrict__ cursor) {
  __shared__ int buf[256];
  __shared__ int carry;
  if (threadIdx.x == 0) carry = 0;
  __syncthreads();
  for (int base = 0; base < NN; base += 256) {
    int i = base + threadIdx.x;
    int v = (i < NN) ? cnt[i] : 0;
    buf[threadIdx.x] = v;
    __syncthreads();
#pragma unroll
    for (int o = 1; o < 256; o <<= 1) {
      int t = (threadIdx.x >= o) ? buf[threadIdx.x - o] : 0;
      __syncthreads();
      buf[threadIdx.x] += t;
      __syncthreads();
    }
    int incl = buf[threadIdx.x];
    int c0 = carry;
    if (i < NN) { int ex = c0 + incl - v; off[i] = ex; cursor[i] = ex; }
    __syncthreads();
    if (threadIdx.x == 255) carry = c0 + incl;
    __syncthreads();
  }
}

__global__ __launch_bounds__(256)
void bucket_kernel(const int* __restrict__ src, const int* __restrict__ dst,
                   int* __restrict__ cursor, int* __restrict__ es) {
  int e = blockIdx.x * 256 + threadIdx.x;
  if (e < NE) {
    int p = atomicAdd(&cursor[dst[e]], 1);
    es[p] = src[e];
  }
}

// ================= gather-aggregate (replaces atomic scatter) =================
// layer 1: C=128, x f32. One 64-lane wave per node, 2 channels/lane.
__global__ __launch_bounds__(256)
void gather_l1(const float* __restrict__ x, const float* __restrict__ pos,
               const int* __restrict__ off, const int* __restrict__ cnt,
               const int* __restrict__ es,
               const float* __restrict__ Win, const float* __restrict__ bin,
               float* __restrict__ agg) {
  constexpr int C = 128;
  int lane = threadIdx.x & 63;
  int i = blockIdx.x * 4 + (threadIdx.x >> 6);
  if (i >= NN) return;
  int c = lane * 2;
  float w00 = Win[c], w01 = Win[c + 1];
  float w10 = Win[C + c], w11 = Win[C + c + 1];
  float b0 = bin[c], b1 = bin[c + 1];
  float a0 = 0.f, a1 = 0.f;
  float2 pd = *reinterpret_cast<const float2*>(pos + 2 * i);
  int s0 = off[i], n = cnt[i];
  for (int k = 0; k < n; ++k) {
    int s = es[s0 + k];
    float2 ps = *reinterpret_cast<const float2*>(pos + 2 * s);
    float rx = ps.x - pd.x, ry = ps.y - pd.y;
    float2 xv = *reinterpret_cast<const float2*>(x + (size_t)s * C + c);
    float sc0 = fmaxf(fmaf(rx, w00, fmaf(ry, w10, b0)), 0.f);
    float sc1 = fmaxf(fmaf(rx, w01, fmaf(ry, w11, b1)), 0.f);
    a0 = fmaf(sc0, xv.x, a0);
    a1 = fmaf(sc1, xv.y, a1);
  }
  *reinterpret_cast<float2*>(agg + (size_t)i * C + c) = make_float2(a0, a1);
}

// layers 2/3: C=2048, x bf16. One 256-thread block per node, 8 channels/thread.
__global__ __launch_bounds__(256)
void gather_bf16(const __hip_bfloat16* __restrict__ x, const float* __restrict__ pos,
                 const int* __restrict__ off, const int* __restrict__ cnt,
                 const int* __restrict__ es,
                 const float* __restrict__ Win, const float* __restrict__ bin,
                 float* __restrict__ agg) {
  constexpr int C = 2048;
  constexpr int V = 8;
  int i = blockIdx.x;
  int c = threadIdx.x * V;
  float w0[V], w1[V], bb[V], acc[V];
#pragma unroll
  for (int j = 0; j < V; ++j) {
    w0[j] = Win[c + j]; w1[j] = Win[C + c + j]; bb[j] = bin[c + j]; acc[j] = 0.f;
  }
  float2 pd = *reinterpret_cast<const float2*>(pos + 2 * i);
  int s0 = off[i], n = cnt[i];
  for (int k = 0; k < n; ++k) {
    int s = es[s0 + k];
    float2 ps = *reinterpret_cast<const float2*>(pos + 2 * s);
    float rx = ps.x - pd.x, ry = ps.y - pd.y;
    int4 q = *reinterpret_cast<const int4*>(
        reinterpret_cast<const unsigned short*>(x) + (size_t)s * C + c);
    float xv[V] = { blo(q.x), bhi(q.x), blo(q.y), bhi(q.y),
                    blo(q.z), bhi(q.z), blo(q.w), bhi(q.w) };
#pragma unroll
    for (int j = 0; j < V; ++j) {
      float sc = fmaxf(fmaf(rx, w0[j], fmaf(ry, w1[j], bb[j])), 0.f);
      acc[j] = fmaf(sc, xv[j], acc[j]);
    }
  }
  float* ap = agg + (size_t)i * C + c;
  store4(ap, acc);
  store4(ap + 4, acc + 4);
}

// ---------- f32 tiled GEMM: out = relu(A[M,K] @ B[K,N] + bias) ----------
template <typename OT>
__global__ __launch_bounds__(256)
void gemm_bias_relu(const float* __restrict__ A, const float* __restrict__ B,
                    const float* __restrict__ bias, OT* __restrict__ out,
                    int M, int N, int K) {
  __shared__ float As[64][17];
  __shared__ float Bs[16][72];
  const int t = threadIdx.x;
  const int tx = t & 15, ty = t >> 4;
  const int m0 = blockIdx.y * 64, n0 = blockIdx.x * 64;
  const int ar = t >> 2, ak = (t & 3) << 2;
  const int br = t >> 4, bn = (t & 15) << 2;
  float acc[4][4] = {};
  for (int k0 = 0; k0 < K; k0 += 16) {
    float4 av;
    int gm = m0 + ar;
    if (gm < M) av = *reinterpret_cast<const float4*>(&A[(size_t)gm * K + k0 + ak]);
    else av = make_float4(0.f, 0.f, 0.f, 0.f);
    float4 bv = *reinterpret_cast<const float4*>(&B[(size_t)(k0 + br) * N + n0 + bn]);
    As[ar][ak] = av.x; As[ar][ak + 1] = av.y; As[ar][ak + 2] = av.z; As[ar][ak + 3] = av.w;
    *reinterpret_cast<float4*>(&Bs[br][bn]) = bv;
    __syncthreads();
#pragma unroll
    for (int k = 0; k < 16; ++k) {
      float a0 = As[ty * 4 + 0][k], a1 = As[ty * 4 + 1][k];
      float a2 = As[ty * 4 + 2][k], a3 = As[ty * 4 + 3][k];
      float4 b = *reinterpret_cast<const float4*>(&Bs[k][tx * 4]);
      acc[0][0] = fmaf(a0, b.x, acc[0][0]); acc[0][1] = fmaf(a0, b.y, acc[0][1]);
      acc[0][2] = fmaf(a0, b.z, acc[0][2]); acc[0][3] = fmaf(a0, b.w, acc[0][3]);
      acc[1][0] = fmaf(a1, b.x, acc[1][0]); acc[1][1] = fmaf(a1, b.y, acc[1][1]);
      acc[1][2] = fmaf(a1, b.z, acc[1][2]); acc[1][3] = fmaf(a1, b.w, acc[1][3]);
      acc[2][0] = fmaf(a2, b.x, acc[2][0]); acc[2][1] = fmaf(a2, b.y, acc[2][1]);
      acc[2][2] = fmaf(a2, b.z, acc[2][2]); acc[2][3] = fmaf(a2, b.w, acc[2][3]);
      acc[3][0] = fmaf(a3, b.x, acc[3][0]); acc[3][1] = fmaf(a3, b.y, acc[3][1]);
      acc[3][2] = fmaf(a3, b.z, acc[3][2]); acc[3][3] = fmaf(a3, b.w, acc[3][3]);
    }
    __syncthreads();
  }
#pragma unroll
  for (int i = 0; i < 4; ++i) {
    int gm = m0 + ty * 4 + i;
    if (gm < M) {
      float v[4];
#pragma unroll
      for (int j = 0; j < 4; ++j)
        v[j] = fmaxf(acc[i][j] + bias[n0 + tx * 4 + j], 0.f);
      store4(out + (size_t)gm * N + n0 + tx * 4, v);
    }
  }
}

// ---------- row-wise L2 normalize, C=1024 ----------
__global__ __launch_bounds__(256)
void l2norm_kernel(float* __restrict__ out) {
  constexpr int C = 1024;
  float* p = out + (size_t)blockIdx.x * C;
  float4 v = *reinterpret_cast<const float4*>(p + threadIdx.x * 4);
  float s = v.x * v.x + v.y * v.y + v.z * v.z + v.w * v.w;
#pragma unroll
  for (int o = 32; o > 0; o >>= 1) s += __shfl_down(s, o);
  __shared__ float wsum[4];
  if ((threadIdx.x & 63) == 0) wsum[threadIdx.x >> 6] = s;
  __syncthreads();
  float tot = wsum[0] + wsum[1] + wsum[2] + wsum[3];
  float inv = 1.0f / fmaxf(sqrtf(tot), 1e-12f);
  float4 r = make_float4(v.x * inv, v.y * inv, v.z * inv, v.w * inv);
  *reinterpret_cast<float4*>(p + threadIdx.x * 4) = r;
}

extern "C" void kernel_launch(void* const* d_in, const int* in_sizes, int n_in,
                              void* d_out, int out_size, void* d_ws, size_t ws_size,
                              hipStream_t stream) {
  (void)in_sizes; (void)n_in; (void)out_size; (void)ws_size;
  const float* x     = (const float*)d_in[0];
  const float* pos   = (const float*)d_in[1];
  const int*   ei    = (const int*)d_in[2];
  const int*   srcv  = ei;            // edge_index[0] (j)
  const int*   dstv  = ei + NE;       // edge_index[1] (i)
  const float* Win1  = (const float*)d_in[3];
  const float* bin1  = (const float*)d_in[4];
  const float* Wout1 = (const float*)d_in[5];
  const float* bout1 = (const float*)d_in[6];
  const float* Win2  = (const float*)d_in[7];
  const float* bin2  = (const float*)d_in[8];
  const float* Wout2 = (const float*)d_in[9];
  const float* bout2 = (const float*)d_in[10];
  const float* Win3  = (const float*)d_in[11];
  const float* bin3  = (const float*)d_in[12];
  const float* Wout3 = (const float*)d_in[13];
  const float* bout3 = (const float*)d_in[14];
  float* outp = (float*)d_out;

  // workspace layout (total ~123.3 MB, well under proven-safe 164 MB)
  char* ws = (char*)d_ws;
  float* agg = (float*)ws;                                   // 81,920,000 B
  __hip_bfloat16* h1 = (__hip_bfloat16*)(ws + 81920000);     // 40,960,000 B
  int* cnt    = (int*)(ws + 122880000);                      // 40,000 B
  int* off    = (int*)(ws + 122920000);                      // 40,000 B
  int* cursor = (int*)(ws + 122960000);                      // 40,000 B
  int* es     = (int*)(ws + 123000000);                      // 320,000 B
  // h2 (bf16 [NN,2048] = 40.96 MB) lives in d_out; dead before GEMM3 overwrites it
  __hip_bfloat16* h2 = (__hip_bfloat16*)d_out;

  const dim3 blk(256);
  const int eb = (NE + 255) / 256;

  // ---- CSR build (per call; deterministic work) ----
  hipMemsetAsync(cnt, 0, NN * sizeof(int), stream);
  hist_kernel<<<eb, blk, 0, stream>>>(dstv, cnt);
  scan_kernel<<<1, blk, 0, stream>>>(cnt, off, cursor);
  bucket_kernel<<<eb, blk, 0, stream>>>(srcv, dstv, cursor, es);

  // ---- layer 1: 128 -> 2048 ----
  gather_l1<<<(NN + 3) / 4, blk, 0, stream>>>(x, pos, off, cnt, es, Win1, bin1, agg);
  gemm_bias_relu<__hip_bfloat16><<<dim3(2048 / 64, (NN + 63) / 64), blk, 0, stream>>>(
      agg, Wout1, bout1, h1, NN, 2048, 128);

  // ---- layer 2: 2048 -> 2048 ----
  gather_bf16<<<NN, blk, 0, stream>>>(h1, pos, off, cnt, es, Win2, bin2, agg);
  gemm_bias_relu<__hip_bfloat16><<<dim3(2048 / 64, (NN + 63) / 64), blk, 0, stream>>>(
      agg, Wout2, bout2, h2, NN, 2048, 2048);

  // ---- layer 3: 2048 -> 1024 ----
  gather_bf16<<<NN, blk, 0, stream>>>(h2, pos, off, cnt, es, Win3, bin3, agg);
  gemm_bias_relu<float><<<dim3(1024 / 64, (NN + 63) / 64), blk, 0, stream>>>(
      agg, Wout3, bout3, outp, NN, 1024, 2048);

  // ---- final L2 normalize ----
  l2norm_kernel<<<NN, blk, 0, stream>>>(outp);
}

// Round 3
// 409.718 us; speedup vs baseline: 15.2300x; 4.8548x over previous
//
#include <hip/hip_runtime.h>
#include <hip/hip_bf16.h>

#define DEVI __device__ __forceinline__

constexpr int NN = 10000;       // nodes
constexpr int NE = 80000;       // edges
constexpr int AGG_ROWS = 10112; // 79 * 128 — pad so M-tail tile loads stay in-bounds

typedef __attribute__((ext_vector_type(8))) short bf16x8;  // 8 bf16 (4 VGPRs)
typedef __attribute__((ext_vector_type(4))) float f32x4;   // MFMA acc

// ---------- bf16 helpers (bit-level, RNE) ----------
DEVI float blo(unsigned int u) {
  union { unsigned int i; float f; } c; c.i = u << 16; return c.f;
}
DEVI float bhi(unsigned int u) {
  union { unsigned int i; float f; } c; c.i = u & 0xffff0000u; return c.f;
}
DEVI unsigned short f2b(float f) {
  union { float f; unsigned int i; } c; c.f = f;
  unsigned int i = c.i;
  return (unsigned short)((i + 0x7fffu + ((i >> 16) & 1u)) >> 16);
}
DEVI void st1(float* p, float v) { *p = v; }
DEVI void st1(unsigned short* p, float v) { *p = f2b(v); }
DEVI void store8b(unsigned short* p, const float v[8]) {
  int4 pk;
  pk.x = (int)((unsigned)f2b(v[0]) | ((unsigned)f2b(v[1]) << 16));
  pk.y = (int)((unsigned)f2b(v[2]) | ((unsigned)f2b(v[3]) << 16));
  pk.z = (int)((unsigned)f2b(v[4]) | ((unsigned)f2b(v[5]) << 16));
  pk.w = (int)((unsigned)f2b(v[6]) | ((unsigned)f2b(v[7]) << 16));
  *reinterpret_cast<int4*>(p) = pk;
}

// async global->LDS, 16B per lane (wave-uniform LDS base + lane*16 pattern)
DEVI void gload16(const void* g, void* l) {
  __builtin_amdgcn_global_load_lds(
      (const __attribute__((address_space(1))) void*)g,
      (__attribute__((address_space(3))) void*)l, 16, 0, 0);
}

// ================= CSR build =================
__global__ __launch_bounds__(256)
void hist_kernel(const int* __restrict__ dst, int* __restrict__ cnt) {
  int e = blockIdx.x * 256 + threadIdx.x;
  if (e < NE) atomicAdd(&cnt[dst[e]], 1);
}

__global__ __launch_bounds__(256)
void scan_kernel(const int* __restrict__ cnt, int* __restrict__ off,
                 int* __restrict__ cursor) {
  __shared__ int buf[256];
  __shared__ int carry;
  if (threadIdx.x == 0) carry = 0;
  __syncthreads();
  for (int base = 0; base < NN; base += 256) {
    int i = base + threadIdx.x;
    int v = (i < NN) ? cnt[i] : 0;
    buf[threadIdx.x] = v;
    __syncthreads();
#pragma unroll
    for (int o = 1; o < 256; o <<= 1) {
      int t = (threadIdx.x >= o) ? buf[threadIdx.x - o] : 0;
      __syncthreads();
      buf[threadIdx.x] += t;
      __syncthreads();
    }
    int incl = buf[threadIdx.x];
    int c0 = carry;
    if (i < NN) { int ex = c0 + incl - v; off[i] = ex; cursor[i] = ex; }
    __syncthreads();
    if (threadIdx.x == 255) carry = c0 + incl;
    __syncthreads();
  }
}

__global__ __launch_bounds__(256)
void bucket_kernel(const int* __restrict__ src, const int* __restrict__ dst,
                   int* __restrict__ cursor, int* __restrict__ es) {
  int e = blockIdx.x * 256 + threadIdx.x;
  if (e < NE) {
    int p = atomicAdd(&cursor[dst[e]], 1);
    es[p] = src[e];
  }
}

// ============ weight convert+transpose: W[K][N] f32 -> WT[N][K] bf16 ============
__global__ __launch_bounds__(256)
void transpose_w(const float* __restrict__ W, unsigned short* __restrict__ WT,
                 int K, int N) {
  __shared__ float tile[32][33];
  int tx = threadIdx.x & 31, ty = threadIdx.x >> 5;  // ty 0..7
  int n0 = blockIdx.x * 32, k0 = blockIdx.y * 32;
#pragma unroll
  for (int j = 0; j < 32; j += 8)
    tile[ty + j][tx] = W[(size_t)(k0 + ty + j) * N + n0 + tx];
  __syncthreads();
#pragma unroll
  for (int j = 0; j < 32; j += 8)
    WT[(size_t)(n0 + ty + j) * K + k0 + tx] = f2b(tile[tx][ty + j]);
}

// ================= gather-aggregate (CSR, no atomics) =================
// layer 1: C=128, x f32. One 64-lane wave per node, 2 ch/lane. bf16 out.
__global__ __launch_bounds__(256)
void gather_l1(const float* __restrict__ x, const float* __restrict__ pos,
               const int* __restrict__ off, const int* __restrict__ cnt,
               const int* __restrict__ es,
               const float* __restrict__ Win, const float* __restrict__ bin,
               unsigned short* __restrict__ agg) {
  constexpr int C = 128;
  int lane = threadIdx.x & 63;
  int i = blockIdx.x * 4 + (threadIdx.x >> 6);
  if (i >= NN) return;
  int c = lane * 2;
  float w00 = Win[c], w01 = Win[c + 1];
  float w10 = Win[C + c], w11 = Win[C + c + 1];
  float b0 = bin[c], b1 = bin[c + 1];
  float a0 = 0.f, a1 = 0.f;
  float2 pd = *reinterpret_cast<const float2*>(pos + 2 * i);
  int s0 = off[i], n = cnt[i];
  for (int k = 0; k < n; ++k) {
    int s = es[s0 + k];
    float2 ps = *reinterpret_cast<const float2*>(pos + 2 * s);
    float rx = ps.x - pd.x, ry = ps.y - pd.y;
    float2 xv = *reinterpret_cast<const float2*>(x + (size_t)s * C + c);
    float sc0 = fmaxf(fmaf(rx, w00, fmaf(ry, w10, b0)), 0.f);
    float sc1 = fmaxf(fmaf(rx, w01, fmaf(ry, w11, b1)), 0.f);
    a0 = fmaf(sc0, xv.x, a0);
    a1 = fmaf(sc1, xv.y, a1);
  }
  unsigned int pk = (unsigned)f2b(a0) | ((unsigned)f2b(a1) << 16);
  *reinterpret_cast<unsigned int*>(agg + (size_t)i * C + c) = pk;
}

// layers 2/3: C=2048, x bf16. One 256-thread block per node, 8 ch/thread. bf16 out.
__global__ __launch_bounds__(256)
void gather_c2048(const unsigned short* __restrict__ x, const float* __restrict__ pos,
                  const int* __restrict__ off, const int* __restrict__ cnt,
                  const int* __restrict__ es,
                  const float* __restrict__ Win, const float* __restrict__ bin,
                  unsigned short* __restrict__ agg) {
  constexpr int C = 2048;
  constexpr int V = 8;
  int i = blockIdx.x;
  int c = threadIdx.x * V;
  float w0[V], w1[V], bb[V], acc[V];
#pragma unroll
  for (int j = 0; j < V; ++j) {
    w0[j] = Win[c + j]; w1[j] = Win[C + c + j]; bb[j] = bin[c + j]; acc[j] = 0.f;
  }
  float2 pd = *reinterpret_cast<const float2*>(pos + 2 * i);
  int s0 = off[i], n = cnt[i];
  for (int k = 0; k < n; ++k) {
    int s = es[s0 + k];
    float2 ps = *reinterpret_cast<const float2*>(pos + 2 * s);
    float rx = ps.x - pd.x, ry = ps.y - pd.y;
    int4 q = *reinterpret_cast<const int4*>(x + (size_t)s * C + c);
    float xv[V] = { blo(q.x), bhi(q.x), blo(q.y), bhi(q.y),
                    blo(q.z), bhi(q.z), blo(q.w), bhi(q.w) };
#pragma unroll
    for (int j = 0; j < V; ++j) {
      float sc = fmaxf(fmaf(rx, w0[j], fmaf(ry, w1[j], bb[j])), 0.f);
      acc[j] = fmaf(sc, xv[j], acc[j]);
    }
  }
  store8b(agg + (size_t)i * C + c, acc);
}

// ============ MFMA GEMM: out = relu(A[M,K] @ BT[N,K]^T + bias) ============
// A, BT bf16 (ushort). 128x128 tile, BK=32, 4 waves (2x2 of 64x64), m97 structure.
template <typename OT>
__global__ __launch_bounds__(256)
void gemm_bt(const unsigned short* __restrict__ A,
             const unsigned short* __restrict__ BT,
             const float* __restrict__ bias, OT* __restrict__ out,
             int M, int N, int K) {
  __shared__ unsigned short As[128 * 32];  // [row][k] linear, 8 KiB
  __shared__ unsigned short Bs[128 * 32];
  const int t = threadIdx.x;
  const int lane = t & 63, wid = t >> 6;
  const int wr = wid >> 1, wc = wid & 1;
  const int m0 = blockIdx.y * 128, n0 = blockIdx.x * 128;

  // staging: 512 chunks of 16B per tile; thread t does chunks t and 256+t
  const int srow = t >> 2;            // 0..63 (it0), +64 (it1)
  const int sks = (t & 3) * 8;        // k element offset
  const unsigned short* gA = A + (size_t)(m0 + srow) * K + sks;
  const unsigned short* gB = BT + (size_t)(n0 + srow) * K + sks;
  unsigned short* lA = As + (size_t)t * 8;   // byte offset t*16
  unsigned short* lB = Bs + (size_t)t * 8;
  const size_t gstep = (size_t)64 * K;

  // fragment bases: lane holds row (lane&15), k-slice (lane>>4)*8
  const unsigned short* pa = As + ((size_t)(wr * 64 + (lane & 15))) * 32 + (lane >> 4) * 8;
  const unsigned short* pb = Bs + ((size_t)(wc * 64 + (lane & 15))) * 32 + (lane >> 4) * 8;

  f32x4 acc[4][4];
#pragma unroll
  for (int i = 0; i < 4; ++i)
#pragma unroll
    for (int j = 0; j < 4; ++j) acc[i][j] = 0.f;

  for (int k0 = 0; k0 < K; k0 += 32) {
    gload16(gA + k0, lA);
    gload16(gA + gstep + k0, lA + 2048);
    gload16(gB + k0, lB);
    gload16(gB + gstep + k0, lB + 2048);
    __syncthreads();   // drains vmcnt(0): LDS tiles ready
    bf16x8 af[4], bfr[4];
#pragma unroll
    for (int f = 0; f < 4; ++f) {
      af[f]  = *reinterpret_cast<const bf16x8*>(pa + f * 16 * 32);
      bfr[f] = *reinterpret_cast<const bf16x8*>(pb + f * 16 * 32);
    }
#pragma unroll
    for (int fm = 0; fm < 4; ++fm)
#pragma unroll
      for (int fn = 0; fn < 4; ++fn)
        acc[fm][fn] = __builtin_amdgcn_mfma_f32_16x16x32_bf16(
            af[fm], bfr[fn], acc[fm][fn], 0, 0, 0);
    __syncthreads();   // all reads done before next stage overwrites
  }

  // epilogue: C/D layout col=lane&15, row=(lane>>4)*4+reg
  const int ccol = lane & 15;
  const int crow = (lane >> 4) * 4;
  float bv[4];
#pragma unroll
  for (int fn = 0; fn < 4; ++fn)
    bv[fn] = bias[n0 + wc * 64 + fn * 16 + ccol];
#pragma unroll
  for (int fm = 0; fm < 4; ++fm) {
    int gm0 = m0 + wr * 64 + fm * 16 + crow;
#pragma unroll
    for (int r = 0; r < 4; ++r) {
      int gm = gm0 + r;
      if (gm < M) {
        size_t base = (size_t)gm * N + n0 + wc * 64 + ccol;
#pragma unroll
        for (int fn = 0; fn < 4; ++fn)
          st1(out + base + fn * 16, fmaxf(acc[fm][fn][r] + bv[fn], 0.f));
      }
    }
  }
}

// ---------- row-wise L2 normalize, C=1024 ----------
__global__ __launch_bounds__(256)
void l2norm_kernel(float* __restrict__ out) {
  constexpr int C = 1024;
  float* p = out + (size_t)blockIdx.x * C;
  float4 v = *reinterpret_cast<const float4*>(p + threadIdx.x * 4);
  float s = v.x * v.x + v.y * v.y + v.z * v.z + v.w * v.w;
#pragma unroll
  for (int o = 32; o > 0; o >>= 1) s += __shfl_down(s, o);
  __shared__ float wsum[4];
  if ((threadIdx.x & 63) == 0) wsum[threadIdx.x >> 6] = s;
  __syncthreads();
  float tot = wsum[0] + wsum[1] + wsum[2] + wsum[3];
  float inv = 1.0f / fmaxf(sqrtf(tot), 1e-12f);
  float4 r = make_float4(v.x * inv, v.y * inv, v.z * inv, v.w * inv);
  *reinterpret_cast<float4*>(p + threadIdx.x * 4) = r;
}

extern "C" void kernel_launch(void* const* d_in, const int* in_sizes, int n_in,
                              void* d_out, int out_size, void* d_ws, size_t ws_size,
                              hipStream_t stream) {
  (void)in_sizes; (void)n_in; (void)out_size; (void)ws_size;
  const float* x     = (const float*)d_in[0];
  const float* pos   = (const float*)d_in[1];
  const int*   ei    = (const int*)d_in[2];
  const int*   srcv  = ei;            // edge_index[0] (j)
  const int*   dstv  = ei + NE;       // edge_index[1] (i)
  const float* Win1  = (const float*)d_in[3];
  const float* bin1  = (const float*)d_in[4];
  const float* Wout1 = (const float*)d_in[5];
  const float* bout1 = (const float*)d_in[6];
  const float* Win2  = (const float*)d_in[7];
  const float* bin2  = (const float*)d_in[8];
  const float* Wout2 = (const float*)d_in[9];
  const float* bout2 = (const float*)d_in[10];
  const float* Win3  = (const float*)d_in[11];
  const float* bin3  = (const float*)d_in[12];
  const float* Wout3 = (const float*)d_in[13];
  const float* bout3 = (const float*)d_in[14];
  float* outp = (float*)d_out;

  // workspace layout (~96 MB; 123 MB proven safe in round 1)
  char* ws = (char*)d_ws;
  unsigned short* aggb = (unsigned short*)ws;                    // 10112*2048*2 = 41,418,752
  unsigned short* h1   = (unsigned short*)(ws + 41418752);       // 10000*2048*2 = 40,960,000
  unsigned short* W2T  = (unsigned short*)(ws + 82378752);       // 2048*2048*2  =  8,388,608
  unsigned short* W3T  = (unsigned short*)(ws + 90767360);       // 1024*2048*2  =  4,194,304
  unsigned short* W1T  = (unsigned short*)(ws + 94961664);       // 2048*128*2   =    524,288
  int* cnt    = (int*)(ws + 95485952);
  int* off    = (int*)(ws + 95525952);
  int* cursor = (int*)(ws + 95565952);
  int* es     = (int*)(ws + 95605952);                           // 320,000
  // h2 bf16 [NN,2048] = 40,960,000 B lives in d_out; dead before GEMM3 overwrites it
  unsigned short* h2 = (unsigned short*)d_out;

  const dim3 blk(256);
  const int eb = (NE + 255) / 256;

  // ---- CSR build ----
  hipMemsetAsync(cnt, 0, NN * sizeof(int), stream);
  hist_kernel<<<eb, blk, 0, stream>>>(dstv, cnt);
  scan_kernel<<<1, blk, 0, stream>>>(cnt, off, cursor);
  bucket_kernel<<<eb, blk, 0, stream>>>(srcv, dstv, cursor, es);

  // ---- weight transposes (f32 -> bf16, [K][N] -> [N][K]) ----
  transpose_w<<<dim3(2048 / 32, 128 / 32),  blk, 0, stream>>>(Wout1, W1T, 128, 2048);
  transpose_w<<<dim3(2048 / 32, 2048 / 32), blk, 0, stream>>>(Wout2, W2T, 2048, 2048);
  transpose_w<<<dim3(1024 / 32, 2048 / 32), blk, 0, stream>>>(Wout3, W3T, 2048, 1024);

  // ---- layer 1: 128 -> 2048 ----
  gather_l1<<<(NN + 3) / 4, blk, 0, stream>>>(x, pos, off, cnt, es, Win1, bin1, aggb);
  gemm_bt<unsigned short><<<dim3(2048 / 128, 79), blk, 0, stream>>>(
      aggb, W1T, bout1, h1, NN, 2048, 128);

  // ---- layer 2: 2048 -> 2048 ----
  gather_c2048<<<NN, blk, 0, stream>>>(h1, pos, off, cnt, es, Win2, bin2, aggb);
  gemm_bt<unsigned short><<<dim3(2048 / 128, 79), blk, 0, stream>>>(
      aggb, W2T, bout2, h2, NN, 2048, 2048);

  // ---- layer 3: 2048 -> 1024 ----
  gather_c2048<<<NN, blk, 0, stream>>>(h2, pos, off, cnt, es, Win3, bin3, aggb);
  gemm_bt<float><<<dim3(1024 / 128, 79), blk, 0, stream>>>(
      aggb, W3T, bout3, outp, NN, 1024, 2048);

  // ---- final L2 normalize ----
  l2norm_kernel<<<NN, blk, 0, stream>>>(outp);
}

// Round 4
// 408.043 us; speedup vs baseline: 15.2925x; 1.0041x over previous
//
#include <hip/hip_runtime.h>
#include <hip/hip_bf16.h>

#define DEVI __device__ __forceinline__

constexpr int NN = 10000;       // nodes
constexpr int NE = 80000;       // edges
constexpr int AGG_ROWS = 10240; // 40 * 256 — pad so 256-row M-tiles stay in-bounds

typedef __attribute__((ext_vector_type(8))) short bf16x8;  // 8 bf16 (4 VGPRs)
typedef __attribute__((ext_vector_type(4))) float f32x4;   // MFMA acc

// ---------- bf16 helpers (bit-level, RNE) ----------
DEVI float blo(unsigned int u) {
  union { unsigned int i; float f; } c; c.i = u << 16; return c.f;
}
DEVI float bhi(unsigned int u) {
  union { unsigned int i; float f; } c; c.i = u & 0xffff0000u; return c.f;
}
DEVI unsigned short f2b(float f) {
  union { float f; unsigned int i; } c; c.f = f;
  unsigned int i = c.i;
  return (unsigned short)((i + 0x7fffu + ((i >> 16) & 1u)) >> 16);
}
DEVI void st1(float* p, float v) { *p = v; }
DEVI void st1(unsigned short* p, float v) { *p = f2b(v); }
DEVI void store8b(unsigned short* p, const float v[8]) {
  int4 pk;
  pk.x = (int)((unsigned)f2b(v[0]) | ((unsigned)f2b(v[1]) << 16));
  pk.y = (int)((unsigned)f2b(v[2]) | ((unsigned)f2b(v[3]) << 16));
  pk.z = (int)((unsigned)f2b(v[4]) | ((unsigned)f2b(v[5]) << 16));
  pk.w = (int)((unsigned)f2b(v[6]) | ((unsigned)f2b(v[7]) << 16));
  *reinterpret_cast<int4*>(p) = pk;
}

// async global->LDS, 16B per lane (wave-uniform LDS base + lane*16 pattern)
DEVI void gload16(const void* g, void* l) {
  __builtin_amdgcn_global_load_lds(
      (const __attribute__((address_space(1))) void*)g,
      (__attribute__((address_space(3))) void*)l, 16, 0, 0);
}

// ================= CSR build =================
__global__ __launch_bounds__(256)
void hist_kernel(const int* __restrict__ dst, int* __restrict__ cnt) {
  int e = blockIdx.x * 256 + threadIdx.x;
  if (e < NE) atomicAdd(&cnt[dst[e]], 1);
}

__global__ __launch_bounds__(256)
void scan_kernel(const int* __restrict__ cnt, int* __restrict__ off,
                 int* __restrict__ cursor) {
  __shared__ int buf[256];
  __shared__ int carry;
  if (threadIdx.x == 0) carry = 0;
  __syncthreads();
  for (int base = 0; base < NN; base += 256) {
    int i = base + threadIdx.x;
    int v = (i < NN) ? cnt[i] : 0;
    buf[threadIdx.x] = v;
    __syncthreads();
#pragma unroll
    for (int o = 1; o < 256; o <<= 1) {
      int t = (threadIdx.x >= o) ? buf[threadIdx.x - o] : 0;
      __syncthreads();
      buf[threadIdx.x] += t;
      __syncthreads();
    }
    int incl = buf[threadIdx.x];
    int c0 = carry;
    if (i < NN) { int ex = c0 + incl - v; off[i] = ex; cursor[i] = ex; }
    __syncthreads();
    if (threadIdx.x == 255) carry = c0 + incl;
    __syncthreads();
  }
}

__global__ __launch_bounds__(256)
void bucket_kernel(const int* __restrict__ src, const int* __restrict__ dst,
                   int* __restrict__ cursor, int* __restrict__ es) {
  int e = blockIdx.x * 256 + threadIdx.x;
  if (e < NE) {
    int p = atomicAdd(&cursor[dst[e]], 1);
    es[p] = src[e];
  }
}

// ============ weight convert+transpose: W[K][N] f32 -> WT[N][K] bf16 ============
__global__ __launch_bounds__(256)
void transpose_w(const float* __restrict__ W, unsigned short* __restrict__ WT,
                 int K, int N) {
  __shared__ float tile[32][33];
  int tx = threadIdx.x & 31, ty = threadIdx.x >> 5;  // ty 0..7
  int n0 = blockIdx.x * 32, k0 = blockIdx.y * 32;
#pragma unroll
  for (int j = 0; j < 32; j += 8)
    tile[ty + j][tx] = W[(size_t)(k0 + ty + j) * N + n0 + tx];
  __syncthreads();
#pragma unroll
  for (int j = 0; j < 32; j += 8)
    WT[(size_t)(n0 + ty + j) * K + k0 + tx] = f2b(tile[tx][ty + j]);
}

// ================= gather-aggregate (CSR, no atomics) =================
// layer 1: C=128, x f32. One 64-lane wave per node, 2 ch/lane. bf16 out.
__global__ __launch_bounds__(256)
void gather_l1(const float* __restrict__ x, const float* __restrict__ pos,
               const int* __restrict__ off, const int* __restrict__ cnt,
               const int* __restrict__ es,
               const float* __restrict__ Win, const float* __restrict__ bin,
               unsigned short* __restrict__ agg) {
  constexpr int C = 128;
  int lane = threadIdx.x & 63;
  int i = blockIdx.x * 4 + (threadIdx.x >> 6);
  if (i >= NN) return;
  int c = lane * 2;
  float w00 = Win[c], w01 = Win[c + 1];
  float w10 = Win[C + c], w11 = Win[C + c + 1];
  float b0 = bin[c], b1 = bin[c + 1];
  float a0 = 0.f, a1 = 0.f;
  float2 pd = *reinterpret_cast<const float2*>(pos + 2 * i);
  int s0 = off[i], n = cnt[i];
  for (int k = 0; k < n; ++k) {
    int s = es[s0 + k];
    float2 ps = *reinterpret_cast<const float2*>(pos + 2 * s);
    float rx = ps.x - pd.x, ry = ps.y - pd.y;
    float2 xv = *reinterpret_cast<const float2*>(x + (size_t)s * C + c);
    float sc0 = fmaxf(fmaf(rx, w00, fmaf(ry, w10, b0)), 0.f);
    float sc1 = fmaxf(fmaf(rx, w01, fmaf(ry, w11, b1)), 0.f);
    a0 = fmaf(sc0, xv.x, a0);
    a1 = fmaf(sc1, xv.y, a1);
  }
  unsigned int pk = (unsigned)f2b(a0) | ((unsigned)f2b(a1) << 16);
  *reinterpret_cast<unsigned int*>(agg + (size_t)i * C + c) = pk;
}

// layers 2/3: C=2048, x bf16. One 256-thread block per node, 8 ch/thread. bf16 out.
__global__ __launch_bounds__(256)
void gather_c2048(const unsigned short* __restrict__ x, const float* __restrict__ pos,
                  const int* __restrict__ off, const int* __restrict__ cnt,
                  const int* __restrict__ es,
                  const float* __restrict__ Win, const float* __restrict__ bin,
                  unsigned short* __restrict__ agg) {
  constexpr int C = 2048;
  constexpr int V = 8;
  int i = blockIdx.x;
  int c = threadIdx.x * V;
  float w0[V], w1[V], bb[V], acc[V];
#pragma unroll
  for (int j = 0; j < V; ++j) {
    w0[j] = Win[c + j]; w1[j] = Win[C + c + j]; bb[j] = bin[c + j]; acc[j] = 0.f;
  }
  float2 pd = *reinterpret_cast<const float2*>(pos + 2 * i);
  int s0 = off[i], n = cnt[i];
  for (int k = 0; k < n; ++k) {
    int s = es[s0 + k];
    float2 ps = *reinterpret_cast<const float2*>(pos + 2 * s);
    float rx = ps.x - pd.x, ry = ps.y - pd.y;
    int4 q = *reinterpret_cast<const int4*>(x + (size_t)s * C + c);
    float xv[V] = { blo(q.x), bhi(q.x), blo(q.y), bhi(q.y),
                    blo(q.z), bhi(q.z), blo(q.w), bhi(q.w) };
#pragma unroll
    for (int j = 0; j < V; ++j) {
      float sc = fmaxf(fmaf(rx, w0[j], fmaf(ry, w1[j], bb[j])), 0.f);
      acc[j] = fmaf(sc, xv[j], acc[j]);
    }
  }
  store8b(agg + (size_t)i * C + c, acc);
}

// ============ 256x256 8-wave phase-split MFMA GEMM ============
// out = relu(A[M,K] @ BT[N,K]^T + bias). A, BT bf16 (ushort).
// BK=32, triple-buffered LDS (96 KiB dynamic), staging 2 K-tiles ahead,
// counted vmcnt(6) (never 0 in steady state), raw s_barrier, setprio on MFMA.
// LDS chunk swizzle: logical k-chunk g of row r lives at slot g ^ ((r>>1)&3)
// (applied on pre-swizzled global source AND on fragment-read address).
template <typename OT>
__global__ __launch_bounds__(512, 2)
void gemm256(const unsigned short* __restrict__ A,
             const unsigned short* __restrict__ BT,
             const float* __restrict__ bias, OT* __restrict__ out,
             int M, int N, int K) {
  extern __shared__ unsigned short lds[];  // A: 3*8192, B: 3*8192 elements
  unsigned short* const ldsB = lds + 24576;
  const int t = threadIdx.x;
  const int lane = t & 63, wid = t >> 6;
  const int wr = wid >> 2, wc = wid & 3;          // 2 x 4 wave grid
  const int m0 = blockIdx.y * 256, n0 = blockIdx.x * 256;
  const int nk = K >> 5;

  // staging: 1024 chunks of 16B per 256x32 tile; thread t does chunks t, 512+t
  const int srow = t >> 2;                        // 0..127 (and +128)
  const int scg = (t & 3) ^ ((srow >> 1) & 3);    // swizzled source k-chunk
  const unsigned short* gA = A + (size_t)(m0 + srow) * K + scg * 8;
  const unsigned short* gB = BT + (size_t)(n0 + srow) * K + scg * 8;
  const size_t gH = (size_t)K << 7;               // 128*K elements

#define STAGE_A(buf, kt) { \
    const unsigned short* g_ = gA + ((size_t)(kt) << 5); \
    unsigned short* l_ = lds + (buf) * 8192 + t * 8; \
    gload16(g_, l_); gload16(g_ + gH, l_ + 4096); }
#define STAGE_B(buf, kt) { \
    const unsigned short* g_ = gB + ((size_t)(kt) << 5); \
    unsigned short* l_ = ldsB + (buf) * 8192 + t * 8; \
    gload16(g_, l_); gload16(g_ + gH, l_ + 4096); }

  // fragment read bases: row = base + (lane&15), logical k-chunk = lane>>4,
  // LDS slot = (lane>>4) ^ ((row>>1)&3); row bases are multiples of 16.
  const int frow = lane & 15;
  const int fswz = ((lane >> 4) ^ ((frow >> 1) & 3)) * 8;
  const int paOff = (wr * 128 + frow) * 32 + fswz;
  const int pbOff = (wc * 64 + frow) * 32 + fswz;

  f32x4 acc[8][4];
#pragma unroll
  for (int m = 0; m < 8; ++m)
#pragma unroll
    for (int n = 0; n < 4; ++n) acc[m][n] = 0.f;

  // prologue: stage K-tiles 0 and 1 (8 loads outstanding)
  STAGE_A(0, 0); STAGE_B(0, 0);
  STAGE_A(1, 1); STAGE_B(1, 1);

  int cur = 0;
  for (int kt = 0; kt < nk; ++kt) {
    int nxt = cur + 2; if (nxt >= 3) nxt -= 3;
    // ---- phase A: stage A(kt+2) | drain kt's loads | MFMA m=0..3 ----
    if (kt + 2 < nk) {
      STAGE_A(nxt, kt + 2);
      asm volatile("s_waitcnt vmcnt(6)" ::: "memory");
    } else if (kt + 1 < nk) {
      asm volatile("s_waitcnt vmcnt(4)" ::: "memory");
    } else {
      asm volatile("s_waitcnt vmcnt(0)" ::: "memory");
    }
    asm volatile("s_barrier" ::: "memory");
    const unsigned short* pa = lds + cur * 8192 + paOff;
    const unsigned short* pb = ldsB + cur * 8192 + pbOff;
    bf16x8 bf[4], af[4];
#pragma unroll
    for (int n = 0; n < 4; ++n)
      bf[n] = *reinterpret_cast<const bf16x8*>(pb + n * 512);
#pragma unroll
    for (int m = 0; m < 4; ++m)
      af[m] = *reinterpret_cast<const bf16x8*>(pa + m * 512);
    __builtin_amdgcn_s_setprio(1);
#pragma unroll
    for (int m = 0; m < 4; ++m)
#pragma unroll
      for (int n = 0; n < 4; ++n)
        acc[m][n] = __builtin_amdgcn_mfma_f32_16x16x32_bf16(
            af[m], bf[n], acc[m][n], 0, 0, 0);
    __builtin_amdgcn_s_setprio(0);
    // ---- phase B: stage B(kt+2) | MFMA m=4..7 ----
    if (kt + 2 < nk) STAGE_B(nxt, kt + 2);
#pragma unroll
    for (int m = 0; m < 4; ++m)
      af[m] = *reinterpret_cast<const bf16x8*>(pa + (4 + m) * 512);
    __builtin_amdgcn_s_setprio(1);
#pragma unroll
    for (int m = 0; m < 4; ++m)
#pragma unroll
      for (int n = 0; n < 4; ++n)
        acc[4 + m][n] = __builtin_amdgcn_mfma_f32_16x16x32_bf16(
            af[m], bf[n], acc[4 + m][n], 0, 0, 0);
    __builtin_amdgcn_s_setprio(0);
    asm volatile("s_barrier" ::: "memory");  // reads of cur done before overwrite
    cur = cur + 1 == 3 ? 0 : cur + 1;
  }
#undef STAGE_A
#undef STAGE_B

  // epilogue: C/D layout col=lane&15, row=(lane>>4)*4+reg
  const int ccol = lane & 15;
  const int crow = (lane >> 4) * 4;
  float bv[4];
#pragma unroll
  for (int n = 0; n < 4; ++n)
    bv[n] = bias[n0 + wc * 64 + n * 16 + ccol];
#pragma unroll
  for (int m = 0; m < 8; ++m) {
    int gm0 = m0 + wr * 128 + m * 16 + crow;
#pragma unroll
    for (int r = 0; r < 4; ++r) {
      int gm = gm0 + r;
      if (gm < M) {
        size_t base = (size_t)gm * N + n0 + wc * 64 + ccol;
#pragma unroll
        for (int n = 0; n < 4; ++n)
          st1(out + base + n * 16, fmaxf(acc[m][n][r] + bv[n], 0.f));
      }
    }
  }
}

// ---------- row-wise L2 normalize, C=1024 ----------
__global__ __launch_bounds__(256)
void l2norm_kernel(float* __restrict__ out) {
  constexpr int C = 1024;
  float* p = out + (size_t)blockIdx.x * C;
  float4 v = *reinterpret_cast<const float4*>(p + threadIdx.x * 4);
  float s = v.x * v.x + v.y * v.y + v.z * v.z + v.w * v.w;
#pragma unroll
  for (int o = 32; o > 0; o >>= 1) s += __shfl_down(s, o);
  __shared__ float wsum[4];
  if ((threadIdx.x & 63) == 0) wsum[threadIdx.x >> 6] = s;
  __syncthreads();
  float tot = wsum[0] + wsum[1] + wsum[2] + wsum[3];
  float inv = 1.0f / fmaxf(sqrtf(tot), 1e-12f);
  float4 r = make_float4(v.x * inv, v.y * inv, v.z * inv, v.w * inv);
  *reinterpret_cast<float4*>(p + threadIdx.x * 4) = r;
}

extern "C" void kernel_launch(void* const* d_in, const int* in_sizes, int n_in,
                              void* d_out, int out_size, void* d_ws, size_t ws_size,
                              hipStream_t stream) {
  (void)in_sizes; (void)n_in; (void)out_size; (void)ws_size;
  const float* x     = (const float*)d_in[0];
  const float* pos   = (const float*)d_in[1];
  const int*   ei    = (const int*)d_in[2];
  const int*   srcv  = ei;            // edge_index[0] (j)
  const int*   dstv  = ei + NE;       // edge_index[1] (i)
  const float* Win1  = (const float*)d_in[3];
  const float* bin1  = (const float*)d_in[4];
  const float* Wout1 = (const float*)d_in[5];
  const float* bout1 = (const float*)d_in[6];
  const float* Win2  = (const float*)d_in[7];
  const float* bin2  = (const float*)d_in[8];
  const float* Wout2 = (const float*)d_in[9];
  const float* bout2 = (const float*)d_in[10];
  const float* Win3  = (const float*)d_in[11];
  const float* bin3  = (const float*)d_in[12];
  const float* Wout3 = (const float*)d_in[13];
  const float* bout3 = (const float*)d_in[14];
  float* outp = (float*)d_out;

  // workspace layout (~96.4 MB; 123 MB proven safe in round 1)
  char* ws = (char*)d_ws;
  unsigned short* aggb = (unsigned short*)ws;                    // 10240*2048*2 = 41,943,040
  unsigned short* h1   = (unsigned short*)(ws + 41943040);       // 10000*2048*2 = 40,960,000
  unsigned short* W2T  = (unsigned short*)(ws + 82903040);       // 2048*2048*2  =  8,388,608
  unsigned short* W3T  = (unsigned short*)(ws + 91291648);       // 1024*2048*2  =  4,194,304
  unsigned short* W1T  = (unsigned short*)(ws + 95485952);       // 2048*128*2   =    524,288
  int* cnt    = (int*)(ws + 96010240);
  int* off    = (int*)(ws + 96050240);
  int* cursor = (int*)(ws + 96090240);
  int* es     = (int*)(ws + 96130240);                           // 320,000
  // h2 bf16 [NN,2048] = 40,960,000 B lives in d_out; dead before GEMM3 overwrites it
  unsigned short* h2 = (unsigned short*)d_out;

  // allow 96 KiB dynamic LDS for the GEMM (idempotent host-side call)
  hipFuncSetAttribute((const void*)gemm256<unsigned short>,
                      hipFuncAttributeMaxDynamicSharedMemorySize, 98304);
  hipFuncSetAttribute((const void*)gemm256<float>,
                      hipFuncAttributeMaxDynamicSharedMemorySize, 98304);

  const dim3 blk(256);
  const int eb = (NE + 255) / 256;

  // ---- CSR build ----
  hipMemsetAsync(cnt, 0, NN * sizeof(int), stream);
  hist_kernel<<<eb, blk, 0, stream>>>(dstv, cnt);
  scan_kernel<<<1, blk, 0, stream>>>(cnt, off, cursor);
  bucket_kernel<<<eb, blk, 0, stream>>>(srcv, dstv, cursor, es);

  // ---- weight transposes (f32 -> bf16, [K][N] -> [N][K]) ----
  transpose_w<<<dim3(2048 / 32, 128 / 32),  blk, 0, stream>>>(Wout1, W1T, 128, 2048);
  transpose_w<<<dim3(2048 / 32, 2048 / 32), blk, 0, stream>>>(Wout2, W2T, 2048, 2048);
  transpose_w<<<dim3(1024 / 32, 2048 / 32), blk, 0, stream>>>(Wout3, W3T, 2048, 1024);

  // zero the 240 pad rows of aggb once per call (gathers never touch them)
  hipMemsetAsync(aggb + (size_t)NN * 2048, 0, (size_t)(AGG_ROWS - NN) * 2048 * 2, stream);

  // ---- layer 1: 128 -> 2048 ----
  gather_l1<<<(NN + 3) / 4, blk, 0, stream>>>(x, pos, off, cnt, es, Win1, bin1, aggb);
  gemm256<unsigned short><<<dim3(2048 / 256, AGG_ROWS / 256), 512, 98304, stream>>>(
      aggb, W1T, bout1, h1, NN, 2048, 128);

  // ---- layer 2: 2048 -> 2048 ----
  gather_c2048<<<NN, blk, 0, stream>>>(h1, pos, off, cnt, es, Win2, bin2, aggb);
  gemm256<unsigned short><<<dim3(2048 / 256, AGG_ROWS / 256), 512, 98304, stream>>>(
      aggb, W2T, bout2, h2, NN, 2048, 2048);

  // ---- layer 3: 2048 -> 1024 ----
  gather_c2048<<<NN, blk, 0, stream>>>(h2, pos, off, cnt, es, Win3, bin3, aggb);
  gemm256<float><<<dim3(1024 / 256, AGG_ROWS / 256), 512, 98304, stream>>>(
      aggb, W3T, bout3, outp, NN, 1024, 2048);

  // ---- final L2 normalize ----
  l2norm_kernel<<<NN, blk, 0, stream>>>(outp);
}